// Round 9
// baseline (262.344 us; speedup 1.0000x reference)
//
#include <hip/hip_runtime.h>
#include <math.h>

#define NXY    192
#define CELLS  (NXY*NXY)
#define NBATCH 4
#define NSTEPS 256
#define TCH    16                 // steps per chunk (= halo radius)
#define NCHUNK (NSTEPS/TCH)       // 16
#define TPB    512                // 8 waves
#define NW     8
#define RPL    5                  // rows per wave (40-row window / 8 waves)
#define OUTR   3                  // out rows per tile (3-row tiles)
#define BI_N   64                 // row-tiles per (batch,col)
#define NBLKS  512                // 64 row-tiles x 2 col-tiles x 4 batches
#define NDEP   30                 // (2*7+1) row-tiles x 2 col-tiles
// in-tile 128 cols x 40 rows; out-tile 96 cols x 3 rows (window rows [17,20))
// 2 blocks/CU co-resident: one block's chunk-boundary stall hides behind the
// other block's compute.

// workspace layout (float offsets): 16 state arrays + probe area + flags
#define I_OFF   (16*CELLS)
#define FLG_OFF (I_OFF + 64)      // int flags[NBLKS], monotonic chunk counters

typedef float v2f __attribute__((ext_vector_type(2)));

__device__ __forceinline__ float dpp_up1(float v) {   // lane i <- lane i-1
    int r = __builtin_amdgcn_update_dpp(0, __builtin_bit_cast(int, v),
                                        0x138, 0xf, 0xf, true); // wave_shr:1
    return __builtin_bit_cast(float, r);
}
__device__ __forceinline__ float dpp_dn1(float v) {   // lane i <- lane i+1
    int r = __builtin_amdgcn_update_dpp(0, __builtin_bit_cast(int, v),
                                        0x130, 0xf, 0xf, true); // wave_shl:1
    return __builtin_bit_cast(float, r);
}

__device__ __forceinline__ float pml_prof(int i) {
    int t;
    if (i <= 20)            t = 20 - i;
    else if (i >= NXY - 21) t = i - (NXY - 21);
    else                    return 0.0f;
    float u  = (float)t * 0.05f;
    float u2 = u * u;
    return 3.0f * u2 * u2;
}

// Plain launch. Residency: LDS 21.5KB -> 7 blocks/CU capacity, VGPR ~56 ->
// 4+ waves/SIMD; all 512 blocks resident (2/CU) before any spin.
__global__ __launch_bounds__(TPB, 1)
void wave_k(const float* __restrict__ x, const float* __restrict__ rho,
            float* __restrict__ ws, float* __restrict__ out) {
    // XCD-contiguous remap (bijective, 512 = 8 XCD x 64)
    int blk = ((blockIdx.x & 7) << 6) | (blockIdx.x >> 3);
    int b  = blk / 128;               // batch
    int r_ = blk % 128;
    int bi = r_ >> 1, cj = r_ & 1;    // 64 row-tiles x 2 col-tiles
    int I0 = OUTR * bi - 17;          // window row origin (40 rows)
    int J0 = 96 * cj - 16;            // window col origin (128 cols)
    int t  = threadIdx.x;
    int w  = t >> 6;                  // wave 0..7, owns window rows [5w,5w+5)
    int l  = t & 63;                  // lane: local cols 2l, 2l+1
    int row0 = I0 + RPL * w;
    int gj   = J0 + 2 * l;

    int* flags = (int*)(ws + FLG_OFF);
    // dependency set: row-tiles bi-7..bi+7, both col-tiles, same b.
    // Writers of our window span [bi-6, bi+7]; extended to SYMMETRIC +-7 so
    // X in deps(Y) <=> Y in deps(X), which protects the parity-buffer WAR
    // (a producer can't start chunk c+2 until every reader finished c+1).
    // 30 lanes of wave 0 poll (self included, r3-proven harmless).
    int drt = bi + (t >> 1) - 7;
    int dfi = b * 128 + drt * 2 + (t & 1);
    bool dvalid = (t < NDEP) && (drt >= 0) && (drt < BI_N);

    // [parity][top/bot][slot 0..9][lane]; wave w writes slot w+1;
    // reads up from slot w, down from slot w+2; slots 0,9 stay zero.
    __shared__ v2f hb[2][2][NW + 2][64];
    __shared__ float xs[NSTEPS];
    for (int k = t; k < 2 * 2 * (NW + 2) * 64; k += TPB)
        ((v2f*)hb)[k] = (v2f){0.f, 0.f};
    if (t < NSTEPS) xs[t] = x[b * NSTEPS + t];   // this batch's source trace

    bool cok = (gj >= 0 && gj < NXY);

    // ---- K (=a1*c2/H2) and Q (=1-2*a1) computed once, in-register ----
    // (verified: lane-edge DPP zeros only touch window cols 0/127,
    // outside the clean region)
    v2f Ka[RPL], Qa[RPL];
    {
        v2f rv[RPL + 2];
#pragma unroll
        for (int r = 0; r < RPL + 2; r++) {
            int gi = row0 - 1 + r;
            bool ok = cok && gi >= 0 && gi < NXY;
            rv[r] = ok ? *(const v2f*)(rho + gi * NXY + gj) : (v2f){0.f, 0.f};
        }
        const float IH2 = (float)(1.0 / (2.01 * 2.01));
#pragma unroll
        for (int r = 0; r < RPL; r++) {
            int gi = row0 + r;
            v2f rc = rv[r + 1], ru = rv[r], rd = rv[r + 2];
            float lf = dpp_up1(rc.y);
            float rt = dpp_dn1(rc.x);
            float bx = pml_prof(gi);
            v2f K, Q;
            {
                float lpf = 0.5f * rc.x + 0.125f * ((ru.x + rd.x) + (lf + rc.y));
                float p   = 0.5f * (1.0f + tanhf(100.0f * (lpf - 0.5f)));
                float c   = 1.0f - 0.1f * p;
                float by  = pml_prof(gj);
                float bb  = sqrtf(bx * bx + by * by);
                float a1  = 1.0f / (1.0f + 0.5f * bb);
                K.x = a1 * (c * c * IH2);
                Q.x = 1.0f - 2.0f * a1;
            }
            {
                float lpf = 0.5f * rc.y + 0.125f * ((ru.y + rd.y) + (rc.x + rt));
                float p   = 0.5f * (1.0f + tanhf(100.0f * (lpf - 0.5f)));
                float c   = 1.0f - 0.1f * p;
                float by  = pml_prof(gj + 1);
                float bb  = sqrtf(bx * bx + by * by);
                float a1  = 1.0f / (1.0f + 0.5f * bb);
                K.y = a1 * (c * c * IH2);
                Q.y = 1.0f - 2.0f * a1;
            }
            bool ok = cok && gi >= 0 && gi < NXY;
            Ka[r] = ok ? K : (v2f){0.f, 0.f};   // out-of-domain: K=Q=0 -> 0 forever
            Qa[r] = ok ? Q : (v2f){0.f, 0.f};
        }
    }

    // chunk-0 state is identically zero -> registers; buffer parity
    // guarantees write-before-read for every later chunk.
    v2f yc[RPL], yp[RPL];
#pragma unroll
    for (int r = 0; r < RPL; r++) { yc[r] = (v2f){0.f, 0.f}; yp[r] = (v2f){0.f, 0.f}; }

    // source (40,96): window row sr (in-window for bi 6..19), col sc (even)
    int sr = 40 - I0, sc = 96 - J0;
    bool wave_src = (sr >= RPL * w) && (sr < RPL * w + RPL);
    int src_rl = sr - RPL * w;
    float srcm = (2 * l == sc) ? 1.f : 0.f;

    // probes (160,{48,96,144}): row 160 -> out row of bi==53 (rows 159..161),
    // window row 160-I0 = 18 -> wave 3, r=3. Clean all 16 steps (18 in [16,24)).
    int pcl = 2 * l + J0;             // this lane's global .x column
    bool wave_prb = (bi == 53) && (w == 3);
    const int prb_rl = 3;
    bool is_prb = (cj == 0) ? (pcl == 48) : (pcl == 96 || pcl == 144);
    float prbm = is_prb ? 1.f : 0.f;
    float pacc = 0.f;                 // accumulates across ALL chunks

    v2f uph, dnh;
    __syncthreads();                  // hb zero-init + xs visible

// row update: yn = c + Q*(p-c) + K*(S-4c) — packed fp32, 2 DPP per 2 cells
// (r3-proven plain-C core; compiler codegen is at the VALU floor)
#define ROWC(CUR, PRV, rr_, UP, DN, XSV, YN) do {                              \
    v2f cv = CUR[rr_];                                                         \
    float lf0 = dpp_up1(cv.y);                                                 \
    float rt1 = dpp_dn1(cv.x);                                                 \
    v2f h = (v2f){lf0, rt1} + __builtin_shufflevector(cv, cv, 1, 0);           \
    v2f S = ((UP) + (DN)) + h;                                                 \
    YN = cv + Qa[rr_] * (PRV[rr_] - cv) + Ka[rr_] * (S - 4.0f * cv);           \
    if (wave_src && (rr_) == src_rl) YN.x += srcm * (XSV);                     \
    if (wave_prb && (rr_) == prb_rl) { float q = prbm * YN.x; pacc += q * YN.x; } \
} while (0)

// boundary rows first (early LDS write), interior hides it; ghost read after
// barrier is first used next step  (r3-proven order)
#define STEP(CUR, PRV, PH, SIDX) do {                                          \
    v2f t0, t4;                                                                \
    ROWC(CUR, PRV, 0, uph,    CUR[1], xv[SIDX], t0);                           \
    ROWC(CUR, PRV, 4, CUR[3], dnh,    xv[SIDX], t4);                           \
    hb[PH][0][w + 1][l] = t0;                                                  \
    hb[PH][1][w + 1][l] = t4;                                                  \
    PRV[0] = t0; PRV[4] = t4;                                                  \
    _Pragma("unroll")                                                          \
    for (int r = 1; r <= 3; r++) {                                             \
        v2f y;                                                                 \
        ROWC(CUR, PRV, r, CUR[r - 1], CUR[r + 1], xv[SIDX], y);                \
        PRV[r] = y;                                                            \
    }                                                                          \
    __syncthreads();                                                           \
    uph = hb[PH][1][w][l];                                                     \
    dnh = hb[PH][0][w + 2][l];                                                 \
} while (0)

#pragma unroll 1
    for (int chunk = 0; chunk < NCHUNK; chunk++) {
        // source amplitudes for this chunk (LDS broadcast -> registers)
        float xv[TCH];
#pragma unroll
        for (int i = 0; i < TCH; i++) xv[i] = xs[chunk * TCH + i];

        if (chunk) {
            // wait for the <=30 producer blocks to finish chunk-1
            if (dvalid) {
                while (__hip_atomic_load(&flags[dfi], __ATOMIC_RELAXED,
                                         __HIP_MEMORY_SCOPE_AGENT) < chunk) {}
            }
            __syncthreads();

            // reload the 40x128 state window. All producer stores were sc0 sc1
            // (visible at the coherent point = Infinity Cache), so plain
            // coherent loads suffice — NO cache-maintenance fence needed.
            int pin = chunk & 1;
            const float* curg = ws + ((pin * 2 + 0) * NBATCH + b) * CELLS;
            const float* prvg = ws + ((pin * 2 + 1) * NBATCH + b) * CELLS;
            int  idxr[RPL];
            bool okr[RPL];
#pragma unroll
            for (int r = 0; r < RPL; r++) {
                int gi = row0 + r;
                okr[r]  = cok && gi >= 0 && gi < NXY;
                idxr[r] = okr[r] ? gi * NXY + gj : 0;   // safe dummy addr
            }
            v2f c0, c1, c2, c3, c4, p0, p1, p2, p3, p4;
            asm volatile(
                "global_load_dwordx2 %0, %10, off sc0 sc1\n\t"
                "global_load_dwordx2 %1, %11, off sc0 sc1\n\t"
                "global_load_dwordx2 %2, %12, off sc0 sc1\n\t"
                "global_load_dwordx2 %3, %13, off sc0 sc1\n\t"
                "global_load_dwordx2 %4, %14, off sc0 sc1\n\t"
                "global_load_dwordx2 %5, %15, off sc0 sc1\n\t"
                "global_load_dwordx2 %6, %16, off sc0 sc1\n\t"
                "global_load_dwordx2 %7, %17, off sc0 sc1\n\t"
                "global_load_dwordx2 %8, %18, off sc0 sc1\n\t"
                "global_load_dwordx2 %9, %19, off sc0 sc1\n\t"
                "s_waitcnt vmcnt(0)"
                : "=&v"(c0), "=&v"(c1), "=&v"(c2), "=&v"(c3), "=&v"(c4),
                  "=&v"(p0), "=&v"(p1), "=&v"(p2), "=&v"(p3), "=&v"(p4)
                : "v"(curg + idxr[0]), "v"(curg + idxr[1]), "v"(curg + idxr[2]),
                  "v"(curg + idxr[3]), "v"(curg + idxr[4]),
                  "v"(prvg + idxr[0]), "v"(prvg + idxr[1]), "v"(prvg + idxr[2]),
                  "v"(prvg + idxr[3]), "v"(prvg + idxr[4])
                : "memory");
            yc[0] = okr[0] ? c0 : (v2f){0.f, 0.f};
            yc[1] = okr[1] ? c1 : (v2f){0.f, 0.f};
            yc[2] = okr[2] ? c2 : (v2f){0.f, 0.f};
            yc[3] = okr[3] ? c3 : (v2f){0.f, 0.f};
            yc[4] = okr[4] ? c4 : (v2f){0.f, 0.f};
            yp[0] = okr[0] ? p0 : (v2f){0.f, 0.f};
            yp[1] = okr[1] ? p1 : (v2f){0.f, 0.f};
            yp[2] = okr[2] ? p2 : (v2f){0.f, 0.f};
            yp[3] = okr[3] ? p3 : (v2f){0.f, 0.f};
            yp[4] = okr[4] ? p4 : (v2f){0.f, 0.f};
        }

        // prologue halo exchange (parity 0)
        hb[0][0][w + 1][l] = yc[0];
        hb[0][1][w + 1][l] = yc[4];
        __syncthreads();
        uph = hb[0][1][w][l];
        dnh = hb[0][0][w + 2][l];

#pragma unroll
        for (int s2 = 0; s2 < TCH / 2; s2++) {
            STEP(yc, yp, 1, 2 * s2);        // new cur -> yp, writes hb[1]
            STEP(yp, yc, 0, 2 * s2 + 1);    // new cur -> yc, writes hb[0]
        }
        // yc = y(t_end), yp = y(t_end-1); clean on window rows [16,24), cols [16,112)

        if (chunk != NCHUNK - 1) {
            // store out-tile coherently (sc0 sc1 -> Infinity Cache):
            // rows [3bi,3bi+3) (window rows [17,20)), lanes 8..55
            int pout = (chunk & 1) ^ 1;
            float* ncurg = ws + ((pout * 2 + 0) * NBATCH + b) * CELLS;
            float* nprvg = ws + ((pout * 2 + 1) * NBATCH + b) * CELLS;
#pragma unroll
            for (int r = 0; r < RPL; r++) {
                int gi = row0 + r;
                if (gi >= OUTR * bi && gi < OUTR * bi + OUTR && l >= 8 && l < 56) {
                    int idx = gi * NXY + gj;
                    asm volatile(
                        "global_store_dwordx2 %0, %2, off sc0 sc1\n\t"
                        "global_store_dwordx2 %1, %3, off sc0 sc1"
                        :: "v"(ncurg + idx), "v"(nprvg + idx),
                           "v"(yc[r]), "v"(yp[r])
                        : "memory");
                }
            }
        } else {
            // last chunk: publish probe energy (unique writer per (b,pid))
            if (wave_prb && is_prb) {
                float* ip = ws + I_OFF + b * 3 + (pcl / 48 - 1);
                asm volatile("global_store_dword %0, %1, off sc0 sc1"
                             :: "v"(ip), "v"(pacc) : "memory");
            }
        }

        // release (r3-proven): drain this wave's coherent stores, barrier
        // (all waves drained), then publish flag at agent scope.
        asm volatile("s_waitcnt vmcnt(0)" ::: "memory");
        __syncthreads();
        if (t == 0) {
            __hip_atomic_store(&flags[blk], chunk + 1, __ATOMIC_RELAXED,
                               __HIP_MEMORY_SCOPE_AGENT);
        }
    }
#undef STEP
#undef ROWC

    // finalization: block 0 waits for the 8 probe-owning blocks
    // (blk = b*128 + 53*2 + cj), then normalizes. I[] reads agent-coherent.
    if (blk == 0) {
        if (t < 8) {
            int pb = (t >> 1) * 128 + 106 + (t & 1);
            while (__hip_atomic_load(&flags[pb], __ATOMIC_RELAXED,
                                     __HIP_MEMORY_SCOPE_AGENT) < NCHUNK) {}
        }
        __syncthreads();
        if (t < 12) {
            const float* I = ws + I_OFF;
            int bb = t / 3;
            float s = 0.f;
#pragma unroll
            for (int k = 0; k < 3; k++)
                s += __hip_atomic_load(I + 3 * bb + k, __ATOMIC_RELAXED,
                                       __HIP_MEMORY_SCOPE_AGENT);
            float num = __hip_atomic_load(I + t, __ATOMIC_RELAXED,
                                          __HIP_MEMORY_SCOPE_AGENT);
            out[t] = num / s;
        }
    }
}

extern "C" void kernel_launch(void* const* d_in, const int* in_sizes, int n_in,
                              void* d_out, int out_size, void* d_ws, size_t ws_size,
                              hipStream_t stream) {
    const float* x   = (const float*)d_in[0];   // (4,256) fp32
    const float* rho = (const float*)d_in[1];   // (192,192) fp32
    float* ws  = (float*)d_ws;
    float* outp = (float*)d_out;

    // zero the probe area + flags (poisoned between iterations)
    hipMemsetAsync((char*)d_ws + I_OFF * sizeof(float), 0,
                   (64 + NBLKS) * sizeof(float), stream);

    // plain launch: 512 blocks -> 2 co-resident blocks/CU (see kernel comment)
    wave_k<<<dim3(NBLKS), dim3(TPB), 0, stream>>>(x, rho, ws, outp);
}

// Round 10
// 186.159 us; speedup vs baseline: 1.4092x; 1.4092x over previous
//
#include <hip/hip_runtime.h>
#include <math.h>

#define NXY    192
#define CELLS  (NXY*NXY)
#define NBATCH 4
#define NSTEPS 256
#define TCH    16                 // steps per chunk (= halo radius)
#define NCHUNK (NSTEPS/TCH)       // 16
#define TPB    512                // 8 waves -> 2 waves/SIMD
#define NW     8
#define RPL    5                  // rows per wave (40-row window / 8 waves)
#define OUTR   6                  // out rows per tile
#define NBLKS  256                // 32 row-tiles x 2 col-tiles x 4 batches
// in-tile 128 cols x 40 rows; out-tile 96 cols x 6 rows (window rows [17,23))

// workspace layout (float offsets): 16 state arrays + probe area + flags
#define I_OFF   (16*CELLS)
#define FLG_OFF (I_OFF + 64)      // int flags[NBLKS], monotonic chunk counters

typedef float v2f __attribute__((ext_vector_type(2)));

__device__ __forceinline__ float dpp_up1(float v) {   // lane i <- lane i-1
    int r = __builtin_amdgcn_update_dpp(0, __builtin_bit_cast(int, v),
                                        0x138, 0xf, 0xf, true); // wave_shr:1
    return __builtin_bit_cast(float, r);
}
__device__ __forceinline__ float dpp_dn1(float v) {   // lane i <- lane i+1
    int r = __builtin_amdgcn_update_dpp(0, __builtin_bit_cast(int, v),
                                        0x130, 0xf, 0xf, true); // wave_shl:1
    return __builtin_bit_cast(float, r);
}

__device__ __forceinline__ float pml_prof(int i) {
    int t;
    if (i <= 20)            t = 20 - i;
    else if (i >= NXY - 21) t = i - (NXY - 21);
    else                    return 0.0f;
    float u  = (float)t * 0.05f;
    float u2 = u * u;
    return 3.0f * u2 * u2;
}

// Plain launch (r4-proven wall win): co-residency guaranteed by capacity —
// VGPR 56 -> 32 waves/CU, LDS 21.5KB -> 4 blocks/CU; 256 blocks on 256 CUs,
// every block resident before any spin.
__global__ __launch_bounds__(TPB, 1)
void wave_k(const float* __restrict__ x, const float* __restrict__ rho,
            float* __restrict__ ws, float* __restrict__ out) {
    // XCD-contiguous remap (bijective, 256 = 8 XCD x 32)
    int blk = ((blockIdx.x & 7) << 5) | (blockIdx.x >> 3);
    int b  = blk / 64;                // batch
    int r_ = blk % 64;
    int bi = r_ >> 1, cj = r_ & 1;    // 32 row-tiles x 2 col-tiles
    int I0 = OUTR * bi - 17;          // window row origin (40 rows)
    int J0 = 96 * cj - 16;            // window col origin (128 cols)
    int t  = threadIdx.x;
    int w  = t >> 6;                  // wave 0..7, owns window rows [5w,5w+5)
    int l  = t & 63;                  // lane: local cols 2l, 2l+1
    int row0 = I0 + RPL * w;
    int gj   = J0 + 2 * l;

    int* flags = (int*)(ws + FLG_OFF);
    // dependency set: row-tiles bi-3..bi+3 (clamped), both col-tiles, same b.
    // Symmetric relation -> also protects WAR on the parity buffers.
    // (r3-proven: self included, 14 lanes of wave 0 poll.)
    int drt = bi + (t >> 1) - 3;
    int dfi = b * 64 + drt * 2 + (t & 1);
    bool dvalid = (t < 14) && (drt >= 0) && (drt < 32);

    // [parity][top/bot][slot 0..9][lane]; wave w writes slot w+1;
    // reads up from slot w, down from slot w+2; slots 0,9 stay zero.
    __shared__ v2f hb[2][2][NW + 2][64];
    __shared__ float xs[NSTEPS];
    for (int k = t; k < 2 * 2 * (NW + 2) * 64; k += TPB)
        ((v2f*)hb)[k] = (v2f){0.f, 0.f};
    if (t < NSTEPS) xs[t] = x[b * NSTEPS + t];   // this batch's source trace

    bool cok = (gj >= 0 && gj < NXY);

    // ---- K (=a1*c2/H2) and Q (=1-2*a1) computed once, in-register ----
    // (verified: lane-edge DPP zeros only touch window cols 0/127,
    // outside the clean region)
    v2f Ka[RPL], Qa[RPL];
    {
        v2f rv[RPL + 2];
#pragma unroll
        for (int r = 0; r < RPL + 2; r++) {
            int gi = row0 - 1 + r;
            bool ok = cok && gi >= 0 && gi < NXY;
            rv[r] = ok ? *(const v2f*)(rho + gi * NXY + gj) : (v2f){0.f, 0.f};
        }
        const float IH2 = (float)(1.0 / (2.01 * 2.01));
#pragma unroll
        for (int r = 0; r < RPL; r++) {
            int gi = row0 + r;
            v2f rc = rv[r + 1], ru = rv[r], rd = rv[r + 2];
            float lf = dpp_up1(rc.y);
            float rt = dpp_dn1(rc.x);
            float bx = pml_prof(gi);
            v2f K, Q;
            {
                float lpf = 0.5f * rc.x + 0.125f * ((ru.x + rd.x) + (lf + rc.y));
                float p   = 0.5f * (1.0f + tanhf(100.0f * (lpf - 0.5f)));
                float c   = 1.0f - 0.1f * p;
                float by  = pml_prof(gj);
                float bb  = sqrtf(bx * bx + by * by);
                float a1  = 1.0f / (1.0f + 0.5f * bb);
                K.x = a1 * (c * c * IH2);
                Q.x = 1.0f - 2.0f * a1;
            }
            {
                float lpf = 0.5f * rc.y + 0.125f * ((ru.y + rd.y) + (rc.x + rt));
                float p   = 0.5f * (1.0f + tanhf(100.0f * (lpf - 0.5f)));
                float c   = 1.0f - 0.1f * p;
                float by  = pml_prof(gj + 1);
                float bb  = sqrtf(bx * bx + by * by);
                float a1  = 1.0f / (1.0f + 0.5f * bb);
                K.y = a1 * (c * c * IH2);
                Q.y = 1.0f - 2.0f * a1;
            }
            bool ok = cok && gi >= 0 && gi < NXY;
            Ka[r] = ok ? K : (v2f){0.f, 0.f};   // out-of-domain: K=Q=0 -> 0 forever
            Qa[r] = ok ? Q : (v2f){0.f, 0.f};
        }
    }

    // chunk-0 state is identically zero -> registers; buffer parity
    // guarantees write-before-read for every later chunk.
    v2f yc[RPL], yp[RPL];
#pragma unroll
    for (int r = 0; r < RPL; r++) { yc[r] = (v2f){0.f, 0.f}; yp[r] = (v2f){0.f, 0.f}; }

    // source (40,96): window col 96-J0 - always even
    int sr = 40 - I0, sc = 96 - J0;
    bool wave_src = (sr >= RPL * w) && (sr < RPL * w + RPL);
    int src_rl = sr - RPL * w;
    float srcm = (2 * l == sc) ? 1.f : 0.f;

    // probes (160,{48,96,144}): row 160 -> bi==26, window row 21 (wave 4, r=1)
    int pcl = 2 * l + J0;             // this lane's global .x column
    bool wave_prb = (bi == 26) && (w == 4);
    const int prb_rl = 1;
    bool is_prb = (cj == 0) ? (pcl == 48) : (pcl == 96 || pcl == 144);
    float prbm = is_prb ? 1.f : 0.f;
    float pacc = 0.f;                 // accumulates across ALL chunks

    v2f uph, dnh;
    __syncthreads();                  // hb zero-init + xs visible

// row update: yn = c + Q*(p-c) + K*(S-4c) — packed fp32, 2 DPP per 2 cells
// (r3-proven plain-C core; compiler codegen is at the VALU floor — r8)
#define ROWC(CUR, PRV, rr_, UP, DN, XSV, YN) do {                              \
    v2f cv = CUR[rr_];                                                         \
    float lf0 = dpp_up1(cv.y);                                                 \
    float rt1 = dpp_dn1(cv.x);                                                 \
    v2f h = (v2f){lf0, rt1} + __builtin_shufflevector(cv, cv, 1, 0);           \
    v2f S = ((UP) + (DN)) + h;                                                 \
    YN = cv + Qa[rr_] * (PRV[rr_] - cv) + Ka[rr_] * (S - 4.0f * cv);           \
    if (wave_src && (rr_) == src_rl) YN.x += srcm * (XSV);                     \
    if (wave_prb && (rr_) == prb_rl) { float q = prbm * YN.x; pacc += q * YN.x; } \
} while (0)

// boundary rows first (early LDS write), interior hides it; ghost read after
// barrier is first used next step  (r3-proven order)
#define STEP(CUR, PRV, PH, SIDX) do {                                          \
    v2f t0, t4;                                                                \
    ROWC(CUR, PRV, 0, uph,    CUR[1], xv[SIDX], t0);                           \
    ROWC(CUR, PRV, 4, CUR[3], dnh,    xv[SIDX], t4);                           \
    hb[PH][0][w + 1][l] = t0;                                                  \
    hb[PH][1][w + 1][l] = t4;                                                  \
    PRV[0] = t0; PRV[4] = t4;                                                  \
    _Pragma("unroll")                                                          \
    for (int r = 1; r <= 3; r++) {                                             \
        v2f y;                                                                 \
        ROWC(CUR, PRV, r, CUR[r - 1], CUR[r + 1], xv[SIDX], y);                \
        PRV[r] = y;                                                            \
    }                                                                          \
    __syncthreads();                                                           \
    uph = hb[PH][1][w][l];                                                     \
    dnh = hb[PH][0][w + 2][l];                                                 \
} while (0)

#pragma unroll 1
    for (int chunk = 0; chunk < NCHUNK; chunk++) {
        // source amplitudes for this chunk (LDS broadcast -> registers)
        float xv[TCH];
#pragma unroll
        for (int i = 0; i < TCH; i++) xv[i] = xs[chunk * TCH + i];

        if (chunk) {
            // wait for the <=14 producer blocks to finish chunk-1
            if (dvalid) {
                while (__hip_atomic_load(&flags[dfi], __ATOMIC_RELAXED,
                                         __HIP_MEMORY_SCOPE_AGENT) < chunk) {}
            }
            __syncthreads();

            // reload the 40x128 state window. All producer stores were sc0 sc1
            // (visible at the coherent point = Infinity Cache), so plain
            // coherent loads suffice — NO cache-maintenance fence needed.
            int pin = chunk & 1;
            const float* curg = ws + ((pin * 2 + 0) * NBATCH + b) * CELLS;
            const float* prvg = ws + ((pin * 2 + 1) * NBATCH + b) * CELLS;
            int  idxr[RPL];
            bool okr[RPL];
#pragma unroll
            for (int r = 0; r < RPL; r++) {
                int gi = row0 + r;
                okr[r]  = cok && gi >= 0 && gi < NXY;
                idxr[r] = okr[r] ? gi * NXY + gj : 0;   // safe dummy addr
            }
            v2f c0, c1, c2, c3, c4, p0, p1, p2, p3, p4;
            asm volatile(
                "global_load_dwordx2 %0, %10, off sc0 sc1\n\t"
                "global_load_dwordx2 %1, %11, off sc0 sc1\n\t"
                "global_load_dwordx2 %2, %12, off sc0 sc1\n\t"
                "global_load_dwordx2 %3, %13, off sc0 sc1\n\t"
                "global_load_dwordx2 %4, %14, off sc0 sc1\n\t"
                "global_load_dwordx2 %5, %15, off sc0 sc1\n\t"
                "global_load_dwordx2 %6, %16, off sc0 sc1\n\t"
                "global_load_dwordx2 %7, %17, off sc0 sc1\n\t"
                "global_load_dwordx2 %8, %18, off sc0 sc1\n\t"
                "global_load_dwordx2 %9, %19, off sc0 sc1\n\t"
                "s_waitcnt vmcnt(0)"
                : "=&v"(c0), "=&v"(c1), "=&v"(c2), "=&v"(c3), "=&v"(c4),
                  "=&v"(p0), "=&v"(p1), "=&v"(p2), "=&v"(p3), "=&v"(p4)
                : "v"(curg + idxr[0]), "v"(curg + idxr[1]), "v"(curg + idxr[2]),
                  "v"(curg + idxr[3]), "v"(curg + idxr[4]),
                  "v"(prvg + idxr[0]), "v"(prvg + idxr[1]), "v"(prvg + idxr[2]),
                  "v"(prvg + idxr[3]), "v"(prvg + idxr[4])
                : "memory");
            yc[0] = okr[0] ? c0 : (v2f){0.f, 0.f};
            yc[1] = okr[1] ? c1 : (v2f){0.f, 0.f};
            yc[2] = okr[2] ? c2 : (v2f){0.f, 0.f};
            yc[3] = okr[3] ? c3 : (v2f){0.f, 0.f};
            yc[4] = okr[4] ? c4 : (v2f){0.f, 0.f};
            yp[0] = okr[0] ? p0 : (v2f){0.f, 0.f};
            yp[1] = okr[1] ? p1 : (v2f){0.f, 0.f};
            yp[2] = okr[2] ? p2 : (v2f){0.f, 0.f};
            yp[3] = okr[3] ? p3 : (v2f){0.f, 0.f};
            yp[4] = okr[4] ? p4 : (v2f){0.f, 0.f};
        }

        // prologue halo exchange (parity 0)
        hb[0][0][w + 1][l] = yc[0];
        hb[0][1][w + 1][l] = yc[4];
        __syncthreads();
        uph = hb[0][1][w][l];
        dnh = hb[0][0][w + 2][l];

#pragma unroll
        for (int s2 = 0; s2 < TCH / 2; s2++) {
            STEP(yc, yp, 1, 2 * s2);        // new cur -> yp, writes hb[1]
            STEP(yp, yc, 0, 2 * s2 + 1);    // new cur -> yc, writes hb[0]
        }
        // yc = y(t_end), yp = y(t_end-1); clean on window rows [16,24), cols [16,112)

        if (chunk != NCHUNK - 1) {
            // store out-tile coherently (sc0 sc1 -> Infinity Cache):
            // rows [6bi,6bi+6) (window rows [17,23)), lanes 8..55
            int pout = (chunk & 1) ^ 1;
            float* ncurg = ws + ((pout * 2 + 0) * NBATCH + b) * CELLS;
            float* nprvg = ws + ((pout * 2 + 1) * NBATCH + b) * CELLS;
#pragma unroll
            for (int r = 0; r < RPL; r++) {
                int gi = row0 + r;
                if (gi >= OUTR * bi && gi < OUTR * bi + OUTR && l >= 8 && l < 56) {
                    int idx = gi * NXY + gj;
                    asm volatile(
                        "global_store_dwordx2 %0, %2, off sc0 sc1\n\t"
                        "global_store_dwordx2 %1, %3, off sc0 sc1"
                        :: "v"(ncurg + idx), "v"(nprvg + idx),
                           "v"(yc[r]), "v"(yp[r])
                        : "memory");
                }
            }
        } else {
            // last chunk: publish probe energy (unique writer per (b,pid))
            if (wave_prb && is_prb) {
                float* ip = ws + I_OFF + b * 3 + (pcl / 48 - 1);
                asm volatile("global_store_dword %0, %1, off sc0 sc1"
                             :: "v"(ip), "v"(pacc) : "memory");
            }
        }

        // release (r3-proven): drain this wave's coherent stores, barrier
        // (all waves drained), then publish flag at agent scope.
        asm volatile("s_waitcnt vmcnt(0)" ::: "memory");
        __syncthreads();
        if (t == 0) {
            __hip_atomic_store(&flags[blk], chunk + 1, __ATOMIC_RELAXED,
                               __HIP_MEMORY_SCOPE_AGENT);
        }
    }
#undef STEP
#undef ROWC

    // finalization: block 0 waits for the 8 probe-owning blocks
    // (blk = b*64 + 26*2 + cj), then normalizes. I[] reads agent-coherent.
    if (blk == 0) {
        if (t < 8) {
            int pb = (t >> 1) * 64 + 52 + (t & 1);
            while (__hip_atomic_load(&flags[pb], __ATOMIC_RELAXED,
                                     __HIP_MEMORY_SCOPE_AGENT) < NCHUNK) {}
        }
        __syncthreads();
        if (t < 12) {
            const float* I = ws + I_OFF;
            int bb = t / 3;
            float s = 0.f;
#pragma unroll
            for (int k = 0; k < 3; k++)
                s += __hip_atomic_load(I + 3 * bb + k, __ATOMIC_RELAXED,
                                       __HIP_MEMORY_SCOPE_AGENT);
            float num = __hip_atomic_load(I + t, __ATOMIC_RELAXED,
                                          __HIP_MEMORY_SCOPE_AGENT);
            out[t] = num / s;
        }
    }
}

extern "C" void kernel_launch(void* const* d_in, const int* in_sizes, int n_in,
                              void* d_out, int out_size, void* d_ws, size_t ws_size,
                              hipStream_t stream) {
    const float* x   = (const float*)d_in[0];   // (4,256) fp32
    const float* rho = (const float*)d_in[1];   // (192,192) fp32
    float* ws  = (float*)d_ws;
    float* outp = (float*)d_out;

    // zero the probe area + flags (poisoned between iterations)
    hipMemsetAsync((char*)d_ws + I_OFF * sizeof(float), 0,
                   (64 + NBLKS) * sizeof(float), stream);

    // plain launch: co-residency guaranteed by capacity (see kernel comment)
    wave_k<<<dim3(NBLKS), dim3(TPB), 0, stream>>>(x, rho, ws, outp);
}